// Round 2
// baseline (1440.235 us; speedup 1.0000x reference)
//
#include <hip/hip_runtime.h>

// Fused SIREN INR round 2.
// vs round 1: (a) 64-token tiles -> LDS 64 KB/WG -> 2 WGs/CU co-resident
// (4 waves/SIMD; barrier drain of one WG overlaps the other's GEMM);
// (b) XOR-16B swizzle on the h buffer instead of +8 pad (row stride = 1 KB,
// chunk c stored at c^(t&7); swizzle key lr&7 is per-lane constant);
// (c) epilogue folds 30/(2pi) and bias into one fmaf via pre-scaled biases.

#define L_TOTAL 262144
#define TOK 64
#define THREADS 512
#define C_SC 4.77464829275686f  // 30/(2*pi)

typedef _Float16 f16x8 __attribute__((ext_vector_type(8)));
typedef _Float16 f16x4 __attribute__((ext_vector_type(4)));
typedef float    f32x4 __attribute__((ext_vector_type(4)));

#define N1 (512 * 256)                 // W_first elems
#define N2 (N1 + 5 * 512 * 512)        // + W_hidden
#define N3 (N2 + 16 * 512)             // + W_out padded to 16 rows
#define NBIAS 3072                     // 512 first + 5*512 hidden (scaled f32)

__global__ void convert_weights(const float* __restrict__ Wf,
                                const float* __restrict__ Wh,
                                const float* __restrict__ Wo,
                                const float* __restrict__ bf,
                                const float* __restrict__ bh,
                                _Float16* __restrict__ o,
                                float* __restrict__ biasC) {
  int i = blockIdx.x * blockDim.x + threadIdx.x;
  if (i < N3) {
    float v;
    if (i < N1) {
      v = Wf[i];
    } else if (i < N2) {
      v = Wh[i - N1];
    } else {
      int r = (i - N2) >> 9, c = (i - N2) & 511;
      v = (r < 3) ? Wo[r * 512 + c] : 0.0f;
    }
    o[i] = (_Float16)v;
  } else if (i < N3 + NBIAS) {
    int j = i - N3;
    biasC[j] = (j < 512 ? bf[j] : bh[j - 512]) * C_SC;
  }
}

// One sine layer: h <- sin(30*(W h + b)). M=512 outs (8 waves x 64 feats),
// N=64 tokens (4 ntiles), K templated. A-frags: 16B contiguous global loads
// of fp16 weight rows (L2-resident). B-frags: swizzled ds_read_b128.
template <int K>
__device__ __forceinline__ void sine_layer(const _Float16* __restrict__ W,
                                           const float* __restrict__ biasC,
                                           _Float16* hb, int lr, int lg,
                                           int m0, int s) {
  f32x4 acc[4][4];
#pragma unroll
  for (int mt = 0; mt < 4; ++mt)
#pragma unroll
    for (int nt = 0; nt < 4; ++nt)
      acc[mt][nt] = (f32x4){0.f, 0.f, 0.f, 0.f};

#pragma unroll 2
  for (int ks = 0; ks < K / 32; ++ks) {
    const int k0 = ks * 32 + lg * 8;
    f16x8 a[4], b[4];
#pragma unroll
    for (int mt = 0; mt < 4; ++mt)
      a[mt] = *(const f16x8*)&W[(m0 + mt * 16 + lr) * K + k0];
    const int coff = ((ks * 4 + lg) ^ s) << 3;  // swizzled 16B chunk
#pragma unroll
    for (int nt = 0; nt < 4; ++nt)
      b[nt] = *(const f16x8*)&hb[(nt * 16 + lr) * 512 + coff];
#pragma unroll
    for (int mt = 0; mt < 4; ++mt)
#pragma unroll
      for (int nt = 0; nt < 4; ++nt)
        acc[mt][nt] = __builtin_amdgcn_mfma_f32_16x16x32_f16(
            a[mt], b[nt], acc[mt][nt], 0, 0, 0);
  }
  __syncthreads();  // all reads of hb done before overwrite
#pragma unroll
  for (int mt = 0; mt < 4; ++mt) {
    const int ob = m0 + mt * 16 + lg * 4;  // 4 consecutive out-features
    const f32x4 bb = *(const f32x4*)&biasC[ob];
    const int woff = (((ob >> 3) ^ s) << 3) + (ob & 7);
#pragma unroll
    for (int nt = 0; nt < 4; ++nt) {
      f16x4 hv;
#pragma unroll
      for (int r = 0; r < 4; ++r) {
        float pre = fmaf(acc[mt][nt][r], C_SC, bb[r]);  // revolutions
        hv[r] = (_Float16)__builtin_amdgcn_sinf(__builtin_amdgcn_fractf(pre));
      }
      *(f16x4*)&hb[(nt * 16 + lr) * 512 + woff] = hv;
    }
  }
  __syncthreads();
}

__global__ __launch_bounds__(THREADS, 4) void siren_kernel(
    const float* __restrict__ coords, const float* __restrict__ bff,
    const float* __restrict__ biasC, const float* __restrict__ b_out,
    const _Float16* __restrict__ wf, const _Float16* __restrict__ wh,
    const _Float16* __restrict__ wo, float* __restrict__ out) {
  extern __shared__ _Float16 hb[];  // [TOK][512], XOR-16B swizzled
  const int tid = threadIdx.x;
  const int t0 = blockIdx.x * TOK;

  // ---- Fourier features: f<128 -> sin(2pi proj_f); f>=128 -> cos ----
  {
    const int t = tid >> 3;           // 0..63 token
    const int q = tid & 7;            // feature octant (32 feats each)
    const int st = t & 7;
    const float c0 = coords[(t0 + t) * 3 + 0];
    const float c1 = coords[(t0 + t) * 3 + 1];
    const float c2 = coords[(t0 + t) * 3 + 2];
    const int j0 = (q & 3) * 32;
    const bool is_cos = q >= 4;
    _Float16* hr = &hb[t * 512];
#pragma unroll
    for (int cb = 0; cb < 4; ++cb) {
      f16x8 v;
#pragma unroll
      for (int e = 0; e < 8; ++e) {
        const int j = j0 + cb * 8 + e;
        float r = fmaf(c0, bff[j], fmaf(c1, bff[128 + j], c2 * bff[256 + j]));
        float fr = __builtin_amdgcn_fractf(r);
        v[e] = (_Float16)(is_cos ? __builtin_amdgcn_cosf(fr)
                                 : __builtin_amdgcn_sinf(fr));
      }
      const int f = (is_cos ? 128 : 0) + j0 + cb * 8;
      *(f16x8*)&hr[((f >> 3) ^ st) << 3] = v;
    }
  }
  __syncthreads();

  const int lane = tid & 63;
  const int lr = lane & 15;   // A: weight row / B: token / C: token col
  const int lg = lane >> 4;   // k-group for frags, row-group for C
  const int s = lr & 7;       // per-lane swizzle key (== token&7 of its rows)
  const int m0 = (tid >> 6) * 64;  // wave's 64-feature output slice

  sine_layer<256>(wf, biasC, hb, lr, lg, m0, s);
#pragma unroll 1
  for (int l = 0; l < 5; ++l)
    sine_layer<512>(wh + l * (512 * 512), biasC + 512 + l * 512, hb, lr, lg,
                    m0, s);

  // ---- final linear: out[t][0..2], 16 tokens per wave, waves 0..3 ----
  {
    const int wave = tid >> 6;
    if (wave < 4) {
      f32x4 acc = {0.f, 0.f, 0.f, 0.f};
#pragma unroll
      for (int ks = 0; ks < 16; ++ks) {
        const int k0 = ks * 32 + lg * 8;
        f16x8 a = *(const f16x8*)&wo[lr * 512 + k0];
        f16x8 b =
            *(const f16x8*)&hb[(wave * 16 + lr) * 512 + (((ks * 4 + lg) ^ s) << 3)];
        acc = __builtin_amdgcn_mfma_f32_16x16x32_f16(a, b, acc, 0, 0, 0);
      }
      if (lg == 0) {  // C rows 0..3 live in lanes 0..15; feature = reg idx
        const int t = t0 + wave * 16 + lr;
        out[t * 3 + 0] = acc[0] + b_out[0];
        out[t * 3 + 1] = acc[1] + b_out[1];
        out[t * 3 + 2] = acc[2] + b_out[2];
      }
    }
  }
}

extern "C" void kernel_launch(void* const* d_in, const int* in_sizes, int n_in,
                              void* d_out, int out_size, void* d_ws,
                              size_t ws_size, hipStream_t stream) {
  const float* coords = (const float*)d_in[0];
  const float* bff    = (const float*)d_in[1];
  const float* Wf     = (const float*)d_in[2];
  const float* bf     = (const float*)d_in[3];
  const float* Wh     = (const float*)d_in[4];
  const float* bh     = (const float*)d_in[5];
  const float* Wo     = (const float*)d_in[6];
  const float* bo     = (const float*)d_in[7];
  float* out = (float*)d_out;

  _Float16* w16 = (_Float16*)d_ws;
  float* biasC = (float*)(w16 + N3);  // 16B-aligned (N3*2 % 16 == 0)

  convert_weights<<<(N3 + NBIAS + 255) / 256, 256, 0, stream>>>(
      Wf, Wh, Wo, bf, bh, w16, biasC);

  const size_t lds_bytes = (size_t)TOK * 512 * sizeof(_Float16);  // 65536
  siren_kernel<<<L_TOTAL / TOK, THREADS, lds_bytes, stream>>>(
      coords, bff, biasC, bo, w16, w16 + N1, w16 + N2, out);
}

// Round 3
// 917.301 us; speedup vs baseline: 1.5701x; 1.5701x over previous
//
#include <hip/hip_runtime.h>

// Fused SIREN INR round 3. Round-1 geometry (TOK=128, 512 thr, wave = 64
// feats x 128 tok = 4x8 accs, 1x weight L2 traffic) with:
// (a) chunk-major LDS layout h[chunk=f>>3][token][8 f16]: b-frag ds_read_b128
//     addresses are LINEAR in lane (addr16B = chunk*128 + token) ->
//     conflict-free; FF-encode writes also lane-linear.
// (b) explicit a-frag register double-buffer + fully unrolled k-loop ->
//     global a-loads for k-step ks+1 issue under the MFMAs of ks.
// (c) launch_bounds(512,2) (round 2's (512,4) VGPR squeeze was the regression).

#define L_TOTAL 262144
#define TOK 128
#define THREADS 512
#define C_SC 4.77464829275686f  // 30/(2*pi)

typedef _Float16 f16x8 __attribute__((ext_vector_type(8)));
typedef _Float16 f16x4 __attribute__((ext_vector_type(4)));
typedef float    f32x4 __attribute__((ext_vector_type(4)));

#define N1 (512 * 256)                 // W_first elems
#define N2 (N1 + 5 * 512 * 512)        // + W_hidden
#define N3 (N2 + 16 * 512)             // + W_out padded to 16 rows
#define NBIAS 3072                     // 512 first + 5*512 hidden (pre-scaled)

__global__ void convert_weights(const float* __restrict__ Wf,
                                const float* __restrict__ Wh,
                                const float* __restrict__ Wo,
                                const float* __restrict__ bf,
                                const float* __restrict__ bh,
                                _Float16* __restrict__ o,
                                float* __restrict__ biasC) {
  int i = blockIdx.x * blockDim.x + threadIdx.x;
  if (i < N3) {
    float v;
    if (i < N1) {
      v = Wf[i];
    } else if (i < N2) {
      v = Wh[i - N1];
    } else {
      int r = (i - N2) >> 9, c = (i - N2) & 511;
      v = (r < 3) ? Wo[r * 512 + c] : 0.0f;
    }
    o[i] = (_Float16)v;
  } else if (i < N3 + NBIAS) {
    int j = i - N3;
    biasC[j] = (j < 512 ? bf[j] : bh[j - 512]) * C_SC;
  }
}

// h buffer LDS layout: elem addr = (chunk*128 + token)*8 + (f&7), chunk=f>>3.
__device__ __forceinline__ int h_elem(int chunk, int token) {
  return (chunk * 128 + token) * 8;
}

// One sine layer: h <- sin(30*(W h + b)). M=512 (8 waves x 64 feats),
// N=128 tokens (8 ntiles), K templated (256 first / 512 hidden).
template <int K>
__device__ __forceinline__ void sine_layer(const _Float16* __restrict__ W,
                                           const float* __restrict__ biasC,
                                           _Float16* hb, int lr, int lg,
                                           int m0) {
  constexpr int KS = K / 32;
  f32x4 acc[4][8];
#pragma unroll
  for (int mt = 0; mt < 4; ++mt)
#pragma unroll
    for (int nt = 0; nt < 8; ++nt)
      acc[mt][nt] = (f32x4){0.f, 0.f, 0.f, 0.f};

  // per-mt weight-row base (lane-constant within k-loop; ks adds imm offset)
  const _Float16* wrow[4];
#pragma unroll
  for (int mt = 0; mt < 4; ++mt)
    wrow[mt] = &W[(m0 + mt * 16 + lr) * K + lg * 8];

  f16x8 a[2][4], b[8];
#pragma unroll
  for (int mt = 0; mt < 4; ++mt) a[0][mt] = *(const f16x8*)(wrow[mt]);

#pragma unroll
  for (int ks = 0; ks < KS; ++ks) {
    const int cur = ks & 1;
    // b-frags for this k-step: addr16B = (ks*4+lg)*128 + nt*16 + lr  (linear
    // in lr -> conflict-free ds_read_b128)
#pragma unroll
    for (int nt = 0; nt < 8; ++nt)
      b[nt] = *(const f16x8*)&hb[h_elem(ks * 4 + lg, nt * 16 + lr)];
    // prefetch next k-step's a-frags under this k-step's MFMAs
    if (ks + 1 < KS) {
#pragma unroll
      for (int mt = 0; mt < 4; ++mt)
        a[cur ^ 1][mt] = *(const f16x8*)(wrow[mt] + (ks + 1) * 32);
    }
#pragma unroll
    for (int mt = 0; mt < 4; ++mt)
#pragma unroll
      for (int nt = 0; nt < 8; ++nt)
        acc[mt][nt] = __builtin_amdgcn_mfma_f32_16x16x32_f16(
            a[cur][mt], b[nt], acc[mt][nt], 0, 0, 0);
  }
  __syncthreads();  // all reads of hb done before overwrite

#pragma unroll
  for (int mt = 0; mt < 4; ++mt) {
    const int ob = m0 + mt * 16 + lg * 4;  // 4 consecutive out-features
    const f32x4 bb = *(const f32x4*)&biasC[ob];
    const int wbase = (ob >> 3) * 128 * 8 + (ob & 7);
#pragma unroll
    for (int nt = 0; nt < 8; ++nt) {
      f16x4 hv;
#pragma unroll
      for (int r = 0; r < 4; ++r) {
        float pre = fmaf(acc[mt][nt][r], C_SC, bb[r]);  // revolutions
        hv[r] = (_Float16)__builtin_amdgcn_sinf(__builtin_amdgcn_fractf(pre));
      }
      *(f16x4*)&hb[wbase + (nt * 16 + lr) * 8] = hv;
    }
  }
  __syncthreads();
}

__global__ __launch_bounds__(THREADS, 2) void siren_kernel(
    const float* __restrict__ coords, const float* __restrict__ bff,
    const float* __restrict__ biasC, const float* __restrict__ b_out,
    const _Float16* __restrict__ wf, const _Float16* __restrict__ wh,
    const _Float16* __restrict__ wo, float* __restrict__ out) {
  extern __shared__ _Float16 hb[];  // chunk-major: [64 chunks][128 tok][8]
  const int tid = threadIdx.x;
  const int t0 = blockIdx.x * TOK;

  // ---- Fourier features: chunks q*4+cb (sin), 16+q*4+cb (cos) ----
  {
    const int t = tid & 127;   // token (wave = 64 consecutive tokens)
    const int q = tid >> 7;    // feature octant: proj j in [q*32, q*32+32)
    const float c0 = coords[(t0 + t) * 3 + 0];
    const float c1 = coords[(t0 + t) * 3 + 1];
    const float c2 = coords[(t0 + t) * 3 + 2];
#pragma unroll
    for (int cb = 0; cb < 4; ++cb) {
      f16x8 sv, cv;
#pragma unroll
      for (int e = 0; e < 8; ++e) {
        const int j = q * 32 + cb * 8 + e;
        float r = fmaf(c0, bff[j], fmaf(c1, bff[128 + j], c2 * bff[256 + j]));
        float fr = __builtin_amdgcn_fractf(r);
        sv[e] = (_Float16)__builtin_amdgcn_sinf(fr);
        cv[e] = (_Float16)__builtin_amdgcn_cosf(fr);
      }
      *(f16x8*)&hb[h_elem(q * 4 + cb, t)] = sv;        // lane-linear store
      *(f16x8*)&hb[h_elem(16 + q * 4 + cb, t)] = cv;
    }
  }
  __syncthreads();

  const int lane = tid & 63;
  const int lr = lane & 15;   // A: weight row / B: token / C: token col
  const int lg = lane >> 4;   // k-group for frags, row-group for C
  const int m0 = (tid >> 6) * 64;  // wave's 64-feature output slice

  sine_layer<256>(wf, biasC, hb, lr, lg, m0);
#pragma unroll 1
  for (int l = 0; l < 5; ++l)
    sine_layer<512>(wh + l * (512 * 512), biasC + 512 + l * 512, hb, lr, lg,
                    m0);

  // ---- final linear: out[t][0..2], 16 tokens per wave, 8 waves ----
  {
    const int wave = tid >> 6;
    f32x4 acc = {0.f, 0.f, 0.f, 0.f};
#pragma unroll
    for (int ks = 0; ks < 16; ++ks) {
      f16x8 a = *(const f16x8*)&wo[lr * 512 + ks * 32 + lg * 8];
      f16x8 b = *(const f16x8*)&hb[h_elem(ks * 4 + lg, wave * 16 + lr)];
      acc = __builtin_amdgcn_mfma_f32_16x16x32_f16(a, b, acc, 0, 0, 0);
    }
    if (lg == 0) {  // C rows 0..3 in lanes 0..15; out-feature = reg idx
      const int t = t0 + wave * 16 + lr;
      out[t * 3 + 0] = acc[0] + b_out[0];
      out[t * 3 + 1] = acc[1] + b_out[1];
      out[t * 3 + 2] = acc[2] + b_out[2];
    }
  }
}

extern "C" void kernel_launch(void* const* d_in, const int* in_sizes, int n_in,
                              void* d_out, int out_size, void* d_ws,
                              size_t ws_size, hipStream_t stream) {
  const float* coords = (const float*)d_in[0];
  const float* bff    = (const float*)d_in[1];
  const float* Wf     = (const float*)d_in[2];
  const float* bf     = (const float*)d_in[3];
  const float* Wh     = (const float*)d_in[4];
  const float* bh     = (const float*)d_in[5];
  const float* Wo     = (const float*)d_in[6];
  const float* bo     = (const float*)d_in[7];
  float* out = (float*)d_out;

  _Float16* w16 = (_Float16*)d_ws;
  float* biasC = (float*)(w16 + N3);  // 16B-aligned (N3*2 % 16 == 0)

  convert_weights<<<(N3 + NBIAS + 255) / 256, 256, 0, stream>>>(
      Wf, Wh, Wo, bf, bh, w16, biasC);

  const size_t lds_bytes = 64 * 128 * 8 * sizeof(_Float16);  // 131072
  siren_kernel<<<L_TOTAL / TOK, THREADS, lds_bytes, stream>>>(
      coords, bff, biasC, bo, w16, w16 + N1, w16 + N2, out);
}